// Round 5
// baseline (191.691 us; speedup 1.0000x reference)
//
#include <hip/hip_runtime.h>

typedef __bf16 bf16x8_t __attribute__((ext_vector_type(8)));
typedef float f32x4_t __attribute__((ext_vector_type(4)));
typedef unsigned short ushort_t;

__device__ __forceinline__ unsigned short f2bf(float f) {
  unsigned u = __float_as_uint(f);
  u = (u + 0x7FFFu + ((u >> 16) & 1u)) >> 16;
  return (unsigned short)u;
}
__device__ __forceinline__ float bf2f(unsigned short h) {
  return __uint_as_float(((unsigned)h) << 16);
}

// async global->LDS, 16B/lane. LDS dest = wave-uniform base + lane*16.
__device__ __forceinline__ void gload16(const void* g, void* l) {
  __builtin_amdgcn_global_load_lds(
      (const __attribute__((address_space(1))) unsigned int*)g,
      (__attribute__((address_space(3))) unsigned int*)l, 16, 0, 0);
}

#define BARRIER() __builtin_amdgcn_s_barrier()
#define LGKM0()                                        \
  do {                                                 \
    asm volatile("s_waitcnt lgkmcnt(0)" ::: "memory"); \
    __builtin_amdgcn_sched_barrier(0);                 \
  } while (0)

// ===========================================================================
// 256x256 NT GEMM — derived 4-phase/K-tile schedule (m201-style, race-free).
// BK=64, 8 waves (2Mx4N), 512 thr, LDS 128KiB (2buf x (A32K+B32K)).
// Phases = (m-half x k-slice); B (4n x 2ks) held in regs for the whole tile:
//   ph0: read A m0-3 ks0 + B ks0 (8 rd); stage A-lo(t+1)->q;  MFMA [0-3][*] ks0
//   ph1: read A m0-3 ks1 + B ks1 (8 rd); stage A-hi(t+1)->q;  MFMA [0-3][*] ks1
//   ph2: read A m4-7 ks0        (4 rd); stage B-lo(t+2)->p;  MFMA [4-7][*] ks0
//   ph3: read A m4-7 ks1        (4 rd); stage B-hi(t+2)->p;  MFMA [4-7][*] ks1
// Every stage lands after its region's last read with a barrier in between.
// Boundary wait derived: A-hi(t+1) is 4 loads deep -> vmcnt(4); tail drains.
// Swizzle: LDS(row,chunk16B)=global(row,chunk^(row&7)); ds_read XORs same.
// ===========================================================================
template<bool OUT_BF16, bool HAS_BIAS>
__global__ __launch_bounds__(512, 2)
void gemm256(const ushort_t* __restrict__ A, const ushort_t* __restrict__ Bt,
             void* __restrict__ Cp, const float* __restrict__ bias,
             int gx, int gy, int K, int lda, int ldb, int ldc,
             long sA, long sB, long sC, float alpha)
{
  __shared__ __align__(16) ushort_t sm[2 * 32768];
  const int tid = threadIdx.x;
  const int lane = tid & 63;
  const int w = tid >> 6;
  const int wr = w >> 2, wc = w & 3;

  // bijective XCD-chunked swizzle (all grids here are %8==0)
  const int per = gridDim.x >> 3;
  int wg = blockIdx.x;
  wg = (wg & 7) * per + (wg >> 3);
  const int bz = wg / (gx * gy);
  const int rr = wg - bz * gx * gy;
  const int by = rr / gx, bx = rr - by * gx;
  const int bm = by * 256, bn = bx * 256;

  const int srr = lane >> 3;
  const int csw = ((lane & 7) ^ srr) << 3;
  const ushort_t* pA = A + (long)bz * sA + (long)(bm + w * 16 + srr) * lda + csw;
  const ushort_t* pB = Bt + (long)bz * sB + (long)(bn + w * 16 + srr) * ldb + csw;

  auto stA = [&](int buf, int h, int t) {  // stage A half h (rows h*128..+127)
    const ushort_t* g = pA + (long)(h * 128) * lda + t * 64;
    ushort_t* d = sm + buf * 32768 + h * 8192 + w * 1024;
    gload16(g, d);
    gload16(g + 8 * lda, d + 512);
  };
  auto stB = [&](int buf, int h, int t) {
    const ushort_t* g = pB + (long)(h * 128) * ldb + t * 64;
    ushort_t* d = sm + buf * 32768 + 16384 + h * 8192 + w * 1024;
    gload16(g, d);
    gload16(g + 8 * ldb, d + 512);
  };

  const int q16 = lane >> 4, x7 = lane & 7;
  const int cx0 = ((0 + q16) ^ x7) << 3;   // ks=0 chunk offset (elems)
  const int cx1 = ((4 + q16) ^ x7) << 3;   // ks=1
  const int abase = wr * 8192 + (lane & 15) * 64;
  const int bbase = 16384 + wc * 4096 + (lane & 15) * 64;

  f32x4_t acc[8][4];
  const f32x4_t z4 = {0.f, 0.f, 0.f, 0.f};
#pragma unroll
  for (int m = 0; m < 8; ++m)
#pragma unroll
    for (int n = 0; n < 4; ++n) acc[m][n] = z4;

  bf16x8_t a0[4], a1[4], b0[4], b1[4];

  // ---- prologue: A(0), B(0), B(1). Need A(0)+B(0): 4 loads (B(1)) after
  // the last needed -> vmcnt(4).
  stA(0, 0, 0); stA(0, 1, 0); stB(0, 0, 0); stB(0, 1, 0);
  stB(1, 0, 1); stB(1, 1, 1);
  asm volatile("s_waitcnt vmcnt(4)" ::: "memory");
  __builtin_amdgcn_sched_barrier(0);
  BARRIER();

#define LDX(off) __builtin_bit_cast(bf16x8_t, *(const uint4*)(s + (off)))

  const int nt = K >> 6;
  for (int t = 0; t < nt; ++t) {
    const int buf = t & 1;
    const ushort_t* s = sm + buf * 32768;

    // ---- ph0: A m0-3 ks0 + B ks0; stage A-lo(t+1)->buf^1; MFMA [0-3][*] ks0
#pragma unroll
    for (int m = 0; m < 4; ++m) a0[m] = LDX(abase + m * 1024 + cx0);
#pragma unroll
    for (int n = 0; n < 4; ++n) b0[n] = LDX(bbase + n * 1024 + cx0);
    if (t + 1 < nt) stA(buf ^ 1, 0, t + 1);
    BARRIER();
    LGKM0();
    __builtin_amdgcn_s_setprio(1);
#pragma unroll
    for (int m = 0; m < 4; ++m)
#pragma unroll
      for (int n = 0; n < 4; ++n)
        acc[m][n] = __builtin_amdgcn_mfma_f32_16x16x32_bf16(a0[m], b0[n], acc[m][n], 0, 0, 0);
    __builtin_amdgcn_s_setprio(0);
    BARRIER();

    // ---- ph1: A m0-3 ks1 + B ks1; stage A-hi(t+1)->buf^1; MFMA [0-3][*] ks1
#pragma unroll
    for (int m = 0; m < 4; ++m) a1[m] = LDX(abase + m * 1024 + cx1);
#pragma unroll
    for (int n = 0; n < 4; ++n) b1[n] = LDX(bbase + n * 1024 + cx1);
    if (t + 1 < nt) stA(buf ^ 1, 1, t + 1);
    BARRIER();
    LGKM0();
    __builtin_amdgcn_s_setprio(1);
#pragma unroll
    for (int m = 0; m < 4; ++m)
#pragma unroll
      for (int n = 0; n < 4; ++n)
        acc[m][n] = __builtin_amdgcn_mfma_f32_16x16x32_bf16(a1[m], b1[n], acc[m][n], 0, 0, 0);
    __builtin_amdgcn_s_setprio(0);
    BARRIER();

    // ---- ph2: A m4-7 ks0; stage B-lo(t+2)->buf (B in regs; last LDS read ph1)
#pragma unroll
    for (int m = 0; m < 4; ++m) a0[m] = LDX(abase + (m + 4) * 1024 + cx0);
    if (t + 2 < nt) stB(buf, 0, t + 2);
    BARRIER();
    LGKM0();
    __builtin_amdgcn_s_setprio(1);
#pragma unroll
    for (int m = 0; m < 4; ++m)
#pragma unroll
      for (int n = 0; n < 4; ++n)
        acc[m + 4][n] = __builtin_amdgcn_mfma_f32_16x16x32_bf16(a0[m], b0[n], acc[m + 4][n], 0, 0, 0);
    __builtin_amdgcn_s_setprio(0);
    BARRIER();

    // ---- ph3: A m4-7 ks1; stage B-hi(t+2)->buf; MFMA; derived boundary wait
#pragma unroll
    for (int m = 0; m < 4; ++m) a1[m] = LDX(abase + (m + 4) * 1024 + cx1);
    if (t + 2 < nt) stB(buf, 1, t + 2);
    BARRIER();
    LGKM0();
    __builtin_amdgcn_s_setprio(1);
#pragma unroll
    for (int m = 0; m < 4; ++m)
#pragma unroll
      for (int n = 0; n < 4; ++n)
        acc[m + 4][n] = __builtin_amdgcn_mfma_f32_16x16x32_bf16(a1[m], b1[n], acc[m + 4][n], 0, 0, 0);
    __builtin_amdgcn_s_setprio(0);
    if (t + 2 < nt) {
      asm volatile("s_waitcnt vmcnt(4)" ::: "memory");   // A(t+1) landed; B(t+2) in flight
      __builtin_amdgcn_sched_barrier(0);
    } else if (t + 1 < nt) {
      asm volatile("s_waitcnt vmcnt(0)" ::: "memory");   // tail drain
      __builtin_amdgcn_sched_barrier(0);
    }
    BARRIER();
  }
#undef LDX

  // ---- epilogue. C/D layout: col=lane&15, row=(lane>>4)*4+i  [m89/m91]
  const long zC = (long)bz * sC;
  const int r0 = q16 * 4;
  const int c0 = lane & 15;
#pragma unroll
  for (int mf = 0; mf < 8; ++mf) {
    const int grow0 = bm + wr * 128 + mf * 16 + r0;
#pragma unroll
    for (int nf = 0; nf < 4; ++nf) {
      const int gcol = bn + wc * 64 + nf * 16 + c0;
      float bv_ = 0.f;
      if constexpr (HAS_BIAS) bv_ = bias[gcol];
#pragma unroll
      for (int i = 0; i < 4; ++i) {
        const float v = acc[mf][nf][i] * alpha + bv_;
        if constexpr (OUT_BF16) {
          ((ushort_t*)Cp)[zC + (long)(grow0 + i) * ldc + gcol] = f2bf(v);
        } else {
          ((float*)Cp)[zC + (long)(grow0 + i) * ldc + gcol] = v;
        }
      }
    }
  }
}

// ===========================================================================
// 128x256 4-phase NT GEMM (full-fill variant for PV & Q) — unchanged round-4.
// ===========================================================================
template<bool OUT_BF16, bool HAS_BIAS>
__global__ __launch_bounds__(512, 2)
void gemm_hs(const ushort_t* __restrict__ A, const ushort_t* __restrict__ Bt,
             void* __restrict__ Cp, const float* __restrict__ bias,
             int gx, int gy, int K, int lda, int ldb, int ldc,
             long sA, long sB, long sC, float alpha)
{
  __shared__ __align__(16) ushort_t sm[2 * 24576];
  const int tid = threadIdx.x;
  const int lane = tid & 63;
  const int w = tid >> 6;
  const int wr = w >> 2, wc = w & 3;

  const int per = gridDim.x >> 3;
  int wg = blockIdx.x;
  wg = (wg & 7) * per + (wg >> 3);
  const int bz = wg / (gx * gy);
  const int rr = wg - bz * gx * gy;
  const int by = rr / gx, bx = rr - by * gx;
  const int bm = by * 128, bn = bx * 256;

  const int srr = lane >> 3;
  const int csw = ((lane & 7) ^ srr) << 3;
  const ushort_t* pA = A + (long)bz * sA + (long)(bm + w * 16 + srr) * lda + csw;
  const ushort_t* pB = Bt + (long)bz * sB + (long)(bn + w * 32 + srr) * ldb + csw;

  auto stA = [&](int buf, int t) {
    const ushort_t* g = pA + t * 64;
    ushort_t* d = sm + buf * 24576 + w * 1024;
    gload16(g, d);
    gload16(g + 8 * lda, d + 512);
  };
  auto stB = [&](int buf, int t) {
    const ushort_t* g = pB + t * 64;
    ushort_t* d = sm + buf * 24576 + 8192 + w * 2048;
    gload16(g, d);
    gload16(g + 8 * ldb, d + 512);
    gload16(g + 16 * ldb, d + 1024);
    gload16(g + 24 * ldb, d + 1536);
  };

  const int q = lane >> 4, x7 = lane & 7;
  const int cx0 = ((0 + q) ^ x7) << 3;
  const int cx1 = ((4 + q) ^ x7) << 3;
  const int abase = wr * 4096 + (lane & 15) * 64;
  const int bbase = 8192 + wc * 4096 + (lane & 15) * 64;

  f32x4_t acc[4][4];
  const f32x4_t z4 = {0.f, 0.f, 0.f, 0.f};
#pragma unroll
  for (int m = 0; m < 4; ++m)
#pragma unroll
    for (int n = 0; n < 4; ++n) acc[m][n] = z4;

  bf16x8_t a01[4], a23[4], blo[4], bhi[4];

  stA(0, 0); stB(0, 0); stA(1, 1);
  asm volatile("s_waitcnt vmcnt(2)" ::: "memory");
  __builtin_amdgcn_sched_barrier(0);
  BARRIER();

#define LDX(off) __builtin_bit_cast(bf16x8_t, *(const uint4*)(s + (off)))

  const int nt = K >> 6;
  for (int t = 0; t < nt; ++t) {
    const int buf = t & 1;
    const ushort_t* s = sm + buf * 24576;

    a01[0] = LDX(abase + cx0);        a01[1] = LDX(abase + cx1);
    a01[2] = LDX(abase + 1024 + cx0); a01[3] = LDX(abase + 1024 + cx1);
    blo[0] = LDX(bbase + cx0);        blo[1] = LDX(bbase + cx1);
    blo[2] = LDX(bbase + 1024 + cx0); blo[3] = LDX(bbase + 1024 + cx1);
    if (t + 1 < nt) stB(buf ^ 1, t + 1);
    BARRIER();
    LGKM0();
    __builtin_amdgcn_s_setprio(1);
#pragma unroll
    for (int mf = 0; mf < 2; ++mf)
#pragma unroll
      for (int nf = 0; nf < 2; ++nf) {
        acc[mf][nf] = __builtin_amdgcn_mfma_f32_16x16x32_bf16(a01[mf * 2], blo[nf * 2], acc[mf][nf], 0, 0, 0);
        acc[mf][nf] = __builtin_amdgcn_mfma_f32_16x16x32_bf16(a01[mf * 2 + 1], blo[nf * 2 + 1], acc[mf][nf], 0, 0, 0);
      }
    __builtin_amdgcn_s_setprio(0);
    BARRIER();

    bhi[0] = LDX(bbase + 2048 + cx0); bhi[1] = LDX(bbase + 2048 + cx1);
    bhi[2] = LDX(bbase + 3072 + cx0); bhi[3] = LDX(bbase + 3072 + cx1);
    BARRIER();
    LGKM0();
    __builtin_amdgcn_s_setprio(1);
#pragma unroll
    for (int mf = 0; mf < 2; ++mf)
#pragma unroll
      for (int nf = 0; nf < 2; ++nf) {
        acc[mf][nf + 2] = __builtin_amdgcn_mfma_f32_16x16x32_bf16(a01[mf * 2], bhi[nf * 2], acc[mf][nf + 2], 0, 0, 0);
        acc[mf][nf + 2] = __builtin_amdgcn_mfma_f32_16x16x32_bf16(a01[mf * 2 + 1], bhi[nf * 2 + 1], acc[mf][nf + 2], 0, 0, 0);
      }
    __builtin_amdgcn_s_setprio(0);
    BARRIER();

    a23[0] = LDX(abase + 2048 + cx0); a23[1] = LDX(abase + 2048 + cx1);
    a23[2] = LDX(abase + 3072 + cx0); a23[3] = LDX(abase + 3072 + cx1);
    BARRIER();
    LGKM0();
    __builtin_amdgcn_s_setprio(1);
#pragma unroll
    for (int mf = 0; mf < 2; ++mf)
#pragma unroll
      for (int nf = 0; nf < 2; ++nf) {
        acc[mf + 2][nf + 2] = __builtin_amdgcn_mfma_f32_16x16x32_bf16(a23[mf * 2], bhi[nf * 2], acc[mf + 2][nf + 2], 0, 0, 0);
        acc[mf + 2][nf + 2] = __builtin_amdgcn_mfma_f32_16x16x32_bf16(a23[mf * 2 + 1], bhi[nf * 2 + 1], acc[mf + 2][nf + 2], 0, 0, 0);
      }
    __builtin_amdgcn_s_setprio(0);
    BARRIER();

    if (t + 2 < nt) stA(buf, t + 2);
    __builtin_amdgcn_s_setprio(1);
#pragma unroll
    for (int mf = 0; mf < 2; ++mf)
#pragma unroll
      for (int nf = 0; nf < 2; ++nf) {
        acc[mf + 2][nf] = __builtin_amdgcn_mfma_f32_16x16x32_bf16(a23[mf * 2], blo[nf * 2], acc[mf + 2][nf], 0, 0, 0);
        acc[mf + 2][nf] = __builtin_amdgcn_mfma_f32_16x16x32_bf16(a23[mf * 2 + 1], blo[nf * 2 + 1], acc[mf + 2][nf], 0, 0, 0);
      }
    __builtin_amdgcn_s_setprio(0);
    if (t + 1 < nt) {
      if (t + 2 < nt) asm volatile("s_waitcnt vmcnt(2)" ::: "memory");
      else            asm volatile("s_waitcnt vmcnt(0)" ::: "memory");
      __builtin_amdgcn_sched_barrier(0);
    }
    BARRIER();
  }
#undef LDX

  const long zC = (long)bz * sC;
  const int r0 = q * 4;
  const int c0 = lane & 15;
#pragma unroll
  for (int mf = 0; mf < 4; ++mf) {
    const int grow0 = bm + wr * 64 + mf * 16 + r0;
#pragma unroll
    for (int nf = 0; nf < 4; ++nf) {
      const int gcol = bn + wc * 64 + nf * 16 + c0;
      float bv_ = 0.f;
      if constexpr (HAS_BIAS) bv_ = bias[gcol];
#pragma unroll
      for (int i = 0; i < 4; ++i) {
        const float v = acc[mf][nf][i] * alpha + bv_;
        if constexpr (OUT_BF16) {
          ((ushort_t*)Cp)[zC + (long)(grow0 + i) * ldc + gcol] = f2bf(v);
        } else {
          ((float*)Cp)[zC + (long)(grow0 + i) * ldc + gcol] = v;
        }
      }
    }
  }
}

// fp32 -> bf16 bulk convert for x and y in one launch (8 elems/thread)
__global__ __launch_bounds__(256)
void conv2(const float* __restrict__ x, const float* __restrict__ y,
           ushort_t* __restrict__ xb, ushort_t* __restrict__ yb) {
  const int b = blockIdx.x;
  const float* in = (b < 4096) ? x : y;
  ushort_t* out = (b < 4096) ? xb : yb;
  const long i = (long)(b & 4095) * 256 + threadIdx.x;
  const float4 a = ((const float4*)in)[i * 2];
  const float4 c = ((const float4*)in)[i * 2 + 1];
  uint4 o;
  o.x = (unsigned)f2bf(a.x) | ((unsigned)f2bf(a.y) << 16);
  o.y = (unsigned)f2bf(a.z) | ((unsigned)f2bf(a.w) << 16);
  o.z = (unsigned)f2bf(c.x) | ((unsigned)f2bf(c.y) << 16);
  o.w = (unsigned)f2bf(c.z) | ((unsigned)f2bf(c.w) << 16);
  ((uint4*)out)[i] = o;
}

// Wt[n][k] = (bf16) W[k][n], D=1024, 3 weights in one launch (z selects)
__global__ __launch_bounds__(256)
void wtrans3(const float* __restrict__ W0, const float* __restrict__ W1,
             const float* __restrict__ W2, ushort_t* __restrict__ T0,
             ushort_t* __restrict__ T1, ushort_t* __restrict__ T2) {
  const float* W = (blockIdx.z == 0) ? W0 : (blockIdx.z == 1) ? W1 : W2;
  ushort_t* Wt = (blockIdx.z == 0) ? T0 : (blockIdx.z == 1) ? T1 : T2;
  __shared__ float tile[32][33];
  const int bx = blockIdx.x * 32;
  const int by = blockIdx.y * 32;
  const int t = threadIdx.x;
  const int c = t & 31, r0 = t >> 5;
#pragma unroll
  for (int i = 0; i < 4; ++i)
    tile[r0 + i * 8][c] = W[(long)(by + r0 + i * 8) * 1024 + bx + c];
  __syncthreads();
#pragma unroll
  for (int i = 0; i < 4; ++i)
    Wt[(long)(bx + r0 + i * 8) * 1024 + by + c] = f2bf(tile[c][r0 + i * 8]);
}

__global__ __launch_bounds__(256)
void bconcat(const float* __restrict__ a, const float* __restrict__ b,
             float* __restrict__ o) {
  const int i = blockIdx.x * 256 + threadIdx.x;
  o[i] = (i < 1024) ? a[i] : b[i - 1024];
}

// bf16 transpose with strides: out[c][r] = in[r][c], 64x64 tiles per batch
__global__ __launch_bounds__(256)
void transpose_bf16(const ushort_t* __restrict__ in, ushort_t* __restrict__ out,
                    int ld_in, int ld_out, long in_bs, long out_bs) {
  __shared__ ushort_t tt[64][65];
  in += (long)blockIdx.z * in_bs;
  out += (long)blockIdx.z * out_bs;
  const int r0 = blockIdx.y * 64, c0 = blockIdx.x * 64;
  const int tc = threadIdx.x & 31;
  const int tr = threadIdx.x >> 5;
#pragma unroll
  for (int i = 0; i < 8; ++i) {
    const unsigned v = *(const unsigned*)(in + (long)(r0 + tr + 8 * i) * ld_in + c0 + tc * 2);
    tt[tr + 8 * i][tc * 2] = (ushort_t)(v & 0xffff);
    tt[tr + 8 * i][tc * 2 + 1] = (ushort_t)(v >> 16);
  }
  __syncthreads();
#pragma unroll
  for (int i = 0; i < 8; ++i) {
    const unsigned v = (unsigned)tt[tc * 2][tr + 8 * i] |
                       ((unsigned)tt[tc * 2 + 1][tr + 8 * i] << 16);
    *(unsigned*)(out + (long)(c0 + tr + 8 * i) * ld_out + r0 + tc * 2) = v;
  }
}

// In-place softmax over rows of S (bf16), 2048 cols, one block per row.
__global__ __launch_bounds__(256)
void softmax_rows(ushort_t* __restrict__ S) {
  const long row = blockIdx.x;
  ushort_t* p = S + row * 2048;
  const int t = threadIdx.x;
  uint4 v = ((uint4*)p)[t];
  ushort_t* hp = (ushort_t*)&v;
  float f[8];
#pragma unroll
  for (int j = 0; j < 8; ++j) f[j] = bf2f(hp[j]);

  float m = f[0];
#pragma unroll
  for (int j = 1; j < 8; ++j) m = fmaxf(m, f[j]);
#pragma unroll
  for (int s = 32; s; s >>= 1) m = fmaxf(m, __shfl_xor(m, s, 64));
  __shared__ float redm[4];
  __shared__ float reds[4];
  const int wave = t >> 6, lane = t & 63;
  if (lane == 0) redm[wave] = m;
  __syncthreads();
  m = fmaxf(fmaxf(redm[0], redm[1]), fmaxf(redm[2], redm[3]));

  float sum = 0.f;
#pragma unroll
  for (int j = 0; j < 8; ++j) { f[j] = __expf(f[j] - m); sum += f[j]; }
#pragma unroll
  for (int s = 32; s; s >>= 1) sum += __shfl_xor(sum, s, 64);
  if (lane == 0) reds[wave] = sum;
  __syncthreads();
  sum = reds[0] + reds[1] + reds[2] + reds[3];
  const float inv = 1.0f / sum;
#pragma unroll
  for (int j = 0; j < 8; ++j) hp[j] = f2bf(f[j] * inv);
  ((uint4*)p)[t] = v;
}

extern "C" void kernel_launch(void* const* d_in, const int* in_sizes, int n_in,
                              void* d_out, int out_size, void* d_ws, size_t ws_size,
                              hipStream_t stream) {
  const float* x  = (const float*)d_in[0];
  const float* y  = (const float*)d_in[1];
  const float* Wq = (const float*)d_in[2];
  const float* bq = (const float*)d_in[3];
  const float* Wk = (const float*)d_in[4];
  const float* bk = (const float*)d_in[5];
  const float* Wv = (const float*)d_in[6];
  const float* bv = (const float*)d_in[7];
  float* out = (float*)d_out;

  const int D = 1024;
  const long MB_ = 1l << 20;

  ushort_t* ws  = (ushort_t*)d_ws;
  ushort_t* Wqt = ws;                    // [1024][1024], 1M
  ushort_t* Wkv = ws + 1 * MB_;          // Wkt||Wvt = [2048][1024], 2M
  ushort_t* Wvt = ws + 2 * MB_;
  ushort_t* Qb  = ws + 3 * MB_;          // [8192][1024], 8M
  ushort_t* KV  = ws + 11 * MB_;         // [8192][2048], 16M
  ushort_t* yb  = ws + 27 * MB_;         // [8192][1024], 8M
  ushort_t* Vt  = ws + 27 * MB_;         // alias yb: [B][1024][2048]
  ushort_t* xb  = ws + 35 * MB_;         // [8192][1024], 8M
  ushort_t* Sb  = ws + 35 * MB_;         // alias xb: [B][2048][2048], 16M
  float*    bkv = (float*)(ws + 51 * MB_);  // [2048]

  dim3 blk(256);

  conv2<<<dim3(8192), blk, 0, stream>>>(x, y, xb, yb);
  wtrans3<<<dim3(32, 32, 3), blk, 0, stream>>>(Wq, Wk, Wv, Wqt, Wkv, Wvt);
  bconcat<<<dim3(8), blk, 0, stream>>>(bk, bv, bkv);

  // Q = xb @ Wqt^T + bq -> [8192][1024]; 128x256 tiles: grid 4x64 = 256
  gemm_hs<true, true><<<dim3(256), dim3(512), 0, stream>>>(
      xb, Wqt, Qb, bq, 4, 64, D, D, D, D, 0, 0, 0, 1.0f);
  // KV = yb @ Wkv^T + bkv -> [8192][2048]; 256x256: grid 8x32 = 256
  gemm256<true, true><<<dim3(256), dim3(512), 0, stream>>>(
      yb, Wkv, KV, bkv, 8, 32, D, D, D, 2048, 0, 0, 0, 1.0f);
  // Vt[b][d][t] = KV[b*2048+t][1024+d]
  transpose_bf16<<<dim3(16, 32, 4), blk, 0, stream>>>(
      KV + 1024, Vt, 2048, 2048, 2048l * 2048, 1024l * 2048);

  // S = (Q_b @ K_b^T)/32 -> bf16 [B][2048][2048]; grid 8x8x4 = 256
  gemm256<true, false><<<dim3(256), dim3(512), 0, stream>>>(
      Qb, KV, Sb, nullptr, 8, 8, D, D, 2048, 2048,
      2048l * 1024, 2048l * 2048, 2048l * 2048, 0.03125f);

  softmax_rows<<<dim3(8192), blk, 0, stream>>>(Sb);

  // out = P_b @ V_b (NT vs Vt [1024][2048]) -> fp32; 128x256: grid 4x16x4=256
  gemm_hs<false, false><<<dim3(256), dim3(512), 0, stream>>>(
      Sb, Vt, out, nullptr, 4, 16, 2048, 2048, 2048, D,
      2048l * 2048, 1024l * 2048, 2048l * 1024, 1.0f);
}